// Round 21
// baseline (1744.368 us; speedup 1.0000x reference)
//
#include <hip/hip_runtime.h>

#define NB 128
#define NT 80
#define NI 4096
#define NH 256
#define G4 1024
#define NV 6000
#define NVP 6016
#define NDEC 40

typedef unsigned short ushort_t;
typedef __attribute__((ext_vector_type(8))) short bf16x8;
typedef __attribute__((ext_vector_type(4))) float f32x4;

__device__ __forceinline__ unsigned short f2bf(float f) {
  unsigned int x = __float_as_uint(f);
  x += 0x7FFFu + ((x >> 16) & 1u);
  return (unsigned short)(x >> 16);
}
__device__ __forceinline__ float bf2f(ushort_t u) {
  return __uint_as_float(((unsigned)u) << 16);
}
__device__ __forceinline__ ushort4 pack4(float4 v) {
  return make_ushort4(f2bf(v.x), f2bf(v.y), f2bf(v.z), f2bf(v.w));
}
// fast activations: __expf + hw rcp (validated R13-R20: absmax unchanged)
__device__ __forceinline__ float ftanh(float x) {
  float xc = fminf(fmaxf(x, -12.f), 12.f);
  float e = __expf(2.f * xc);
  return (e - 1.f) * __builtin_amdgcn_rcpf(e + 1.f);
}
__device__ __forceinline__ float fsig(float x) {
  return __builtin_amdgcn_rcpf(1.f + __expf(-x));
}

// ---------------- cast / small kernels ----------------

__global__ __launch_bounds__(256) void k_cast_x(const float* __restrict__ x,
                                                ushort_t* __restrict__ xb) {
  const int t = blockIdx.x, b = blockIdx.y;
  const float* src = x + ((size_t)b * NT + t) * NI;
  ushort_t* dst = xb + ((size_t)t * NB + b) * NI;
#pragma unroll
  for (int s = 0; s < 4; ++s) {
    int j = s * 1024 + threadIdx.x * 4;
    float4 v = *(const float4*)(src + j);
    *(ushort4*)(dst + j) = pack4(v);
  }
}

__global__ __launch_bounds__(256) void k_cast_pad(const float* __restrict__ s,
                                                  ushort_t* __restrict__ d,
                                                  int nsrc, int ndst) {
  int i = (blockIdx.x * 256 + threadIdx.x) * 4;
  if (i >= ndst) return;
  ushort4 o;
  if (i < nsrc) {
    float4 v = *(const float4*)(s + i);
    o = pack4(v);
  } else {
    o = make_ushort4(0, 0, 0, 0);
  }
  *(ushort4*)(d + i) = o;
}

// o = bf16(a + b)
__global__ __launch_bounds__(256) void k_addw_bf(const float* __restrict__ a,
                                                 const float* __restrict__ b,
                                                 ushort_t* __restrict__ o) {
  int i = (blockIdx.x * 256 + threadIdx.x) * 4;
  float4 va = *(const float4*)(a + i);
  float4 vb = *(const float4*)(b + i);
  va.x += vb.x; va.y += vb.y; va.z += vb.z; va.w += vb.w;
  *(ushort4*)(o + i) = pack4(va);
}

// H1dec[1] -= h2St (bf16, in place; 128x256) — folds decode k=0 into Wsum form
__global__ __launch_bounds__(256) void k_subh(ushort_t* __restrict__ H1,
                                              const ushort_t* __restrict__ h2) {
  int i = (blockIdx.x * 256 + threadIdx.x) * 4;
  ushort_t* p = H1 + (size_t)NB * NH + i;
  const ushort_t* q = h2 + i;
#pragma unroll
  for (int k = 0; k < 4; ++k) p[k] = f2bf(bf2f(p[k]) - bf2f(q[k]));
}

// ---------------- bf16 MFMA GEMM: C = A @ B^T + bias_a + bias_b ----------------

#define GLDS(gp, lp)                                                     \
  __builtin_amdgcn_global_load_lds(                                      \
      (const __attribute__((address_space(1))) unsigned int*)(gp),       \
      (__attribute__((address_space(3))) unsigned int*)(lp), 16, 0, 0)

__global__ __launch_bounds__(256) void k_gemm(
    const ushort_t* __restrict__ A, const ushort_t* __restrict__ Bm,
    float* __restrict__ C, const float* __restrict__ ba,
    const float* __restrict__ bb, int Nreal, int K, int ldc, int mtiles) {
  __shared__ __align__(16) ushort_t Als[128 * 32];
  __shared__ __align__(16) ushort_t Bls[128 * 32];
  const int bid = blockIdx.x;
  const int mt = bid % mtiles, nt = bid / mtiles;
  const size_t m0 = (size_t)mt * 128, n0 = (size_t)nt * 128;
  const int tid = threadIdx.x, wave = tid >> 6, lane = tid & 63;
  const int wm = (wave & 1) * 64, wn = (wave >> 1) * 64;
  const int srow = wave * 16 + (lane >> 2), skcol = (lane & 3) * 8;
  const int fr = lane & 15, kb = (lane >> 4) * 8;

  f32x4 acc[4][4];
#pragma unroll
  for (int i = 0; i < 4; ++i)
#pragma unroll
    for (int j = 0; j < 4; ++j) acc[i][j] = (f32x4){0.f, 0.f, 0.f, 0.f};

  for (int kk = 0; kk < K; kk += 32) {
    __syncthreads();
#pragma unroll
    for (int p = 0; p < 2; ++p) {
      GLDS(A + (m0 + p * 64 + srow) * K + kk + skcol,
           &Als[(p * 64 + wave * 16) * 32]);
      GLDS(Bm + (n0 + p * 64 + srow) * K + kk + skcol,
           &Bls[(p * 64 + wave * 16) * 32]);
    }
    __syncthreads();
    bf16x8 af[4], bfr[4];
#pragma unroll
    for (int i = 0; i < 4; ++i)
      af[i] = *(const bf16x8*)&Als[(wm + i * 16 + fr) * 32 + kb];
#pragma unroll
    for (int j = 0; j < 4; ++j)
      bfr[j] = *(const bf16x8*)&Bls[(wn + j * 16 + fr) * 32 + kb];
#pragma unroll
    for (int i = 0; i < 4; ++i)
#pragma unroll
      for (int j = 0; j < 4; ++j)
        acc[i][j] = __builtin_amdgcn_mfma_f32_16x16x32_bf16(af[i], bfr[j],
                                                            acc[i][j], 0, 0, 0);
  }
  const int cr4 = (lane >> 4) * 4, ccn = lane & 15;
#pragma unroll
  for (int j = 0; j < 4; ++j) {
    int n = (int)n0 + wn + j * 16 + ccn;
    if (n < Nreal) {
      float bv = (ba ? ba[n] : 0.f) + (bb ? bb[n] : 0.f);
#pragma unroll
      for (int i = 0; i < 4; ++i) {
#pragma unroll
        for (int r = 0; r < 4; ++r) {
          size_t m = m0 + wm + i * 16 + cr4 + r;
          C[m * (size_t)ldc + n] = acc[i][j][r] + bv;
        }
      }
    }
  }
}

// ---------------- persistent LSTM chain (chunked; 16 waves/block) -------------
// R20 chunk framework, single change: 16 waves x 16 cols (was 8 x 32).
// Per-wave W-load chain halves (24 vs 48) and waves/SIMD doubles (4 vs 2) —
// the measured step wall is the per-wave serialized W-load chain. Pre-loop
// wr[3][8] array + PIN retained (R14 proved in-loop loads are ~2x worse;
// R13's 16-wave regression used the in-loop form). Builtin MFMA only.

struct ChainArgs {
  const float* gIn0; const float* gIn1; int n0; int tStart; int tEnd;
  const ushort_t* W0;
  const float* biasA; const float* biasB;
  ushort_t* traj0; ushort_t* traj1; int t1bmaj;
  ushort_t* hSt; float* cSt;
};

#define LOAD_WREGS(Wb)                                                        \
  _Pragma("unroll") for (int g = 0; g < 3; ++g)                               \
  _Pragma("unroll") for (int kb = 0; kb < 8; ++kb)                            \
      wr[g][kb] = *(const bf16x8*)((Wb) +                                     \
          (size_t)(g * 256 + cbase + cn) * NH + kb * 32 + kgrp * 8);

#define PIN_W()                                                               \
  _Pragma("unroll") for (int g = 0; g < 3; ++g)                               \
  _Pragma("unroll") for (int kb = 0; kb < 8; ++kb)                            \
      asm volatile("" : "+a"(wr[g][kb]));

#define LOAD_WLDS(Wb)                                                         \
  _Pragma("unroll") for (int kb = 0; kb < 8; ++kb)                            \
      *(bf16x8*)&WL[wv * 4096 + kb * 512 + cn * 32 + kgrp * 8] =              \
          *(const bf16x8*)((Wb) +                                             \
          (size_t)(768 + cbase + cn) * NH + kb * 32 + kgrp * 8);

__device__ __forceinline__ void run_chain(const ChainArgs a, int bg,
                                          ushort_t* WL,
                                          ushort_t (*hTz)[16 * 264]) {
  const int tid = threadIdx.x;
  const int wv = tid >> 6, lane = tid & 63;  // wv 0..15
  const int cn = lane & 15;                  // col-in-group / A batch row
  const int kgrp = lane >> 4;                // 0..3 (k slice)
  const int cbase = wv * 16;
  const int rsel = kgrp & 1;                 // batch-row group for G loads

  bf16x8 wr[3][8];
  LOAD_WREGS(a.W0);
  PIN_W();
  LOAD_WLDS(a.W0);

  // ---- state init / restore (barrier between: R16 race fix) ----
  for (int i = tid; i < 2 * 16 * 264; i += 1024) ((ushort_t*)hTz)[i] = 0;
  __syncthreads();
  float cs[4];
  if (a.tStart == 0) {
#pragma unroll
    for (int i = 0; i < 4; ++i) cs[i] = 0.f;
  } else {
    for (int i = tid; i < 8 * 256; i += 1024) {
      int b = i >> 8, col = i & 255;
      hTz[0][b * 264 + col] = a.hSt[(size_t)(bg * 8 + b) * NH + col];
    }
#pragma unroll
    for (int e = 0; e < 4; ++e)
      cs[e] = a.cSt[(size_t)(bg * 8 + rsel * 4 + e) * NH + cbase + cn];
  }
  __syncthreads();

  int cur = 0;
  for (int t = a.tStart; t < a.tEnd; ++t) {
    const ushort_t* hTc = &hTz[cur][0];
    ushort_t* hTn = &hTz[cur ^ 1][0];
    const float* gseg = (t < a.n0) ? a.gIn0 : a.gIn1;
    const int tt = (t < a.n0) ? t : t - a.n0;
    const int gcol = cbase + cn;

    // ---- G input term ----
    float in_[4][4];
    if (gseg) {
      const float* base = gseg + (size_t)tt * (NB * G4);
#pragma unroll
      for (int g = 0; g < 4; ++g)
#pragma unroll
        for (int e = 0; e < 4; ++e)
          in_[g][e] = base[(size_t)(bg * 8 + rsel * 4 + e) * G4 + g * 256 + gcol];
    } else {
#pragma unroll
      for (int g = 0; g < 4; ++g) {
        float b = a.biasA[g * 256 + gcol] + a.biasB[g * 256 + gcol];
#pragma unroll
        for (int e = 0; e < 4; ++e) in_[g][e] = b;
      }
    }
    // ---- A fragments ----
    bf16x8 af[8];
#pragma unroll
    for (int kb = 0; kb < 8; ++kb)
      af[kb] = *(const bf16x8*)&hTc[cn * 264 + kb * 32 + kgrp * 8];
    // ---- MFMA: gates i,f,g from regs; o from persistent LDS ----
    f32x4 acc[4];
#pragma unroll
    for (int g = 0; g < 4; ++g) acc[g] = (f32x4){0.f, 0.f, 0.f, 0.f};
#pragma unroll
    for (int kb = 0; kb < 8; ++kb) {
      bf16x8 bo = *(const bf16x8*)&WL[wv * 4096 + kb * 512 + cn * 32 + kgrp * 8];
      acc[0] = __builtin_amdgcn_mfma_f32_16x16x32_bf16(af[kb], wr[0][kb],
                                                       acc[0], 0, 0, 0);
      acc[1] = __builtin_amdgcn_mfma_f32_16x16x32_bf16(af[kb], wr[1][kb],
                                                       acc[1], 0, 0, 0);
      acc[2] = __builtin_amdgcn_mfma_f32_16x16x32_bf16(af[kb], wr[2][kb],
                                                       acc[2], 0, 0, 0);
      acc[3] = __builtin_amdgcn_mfma_f32_16x16x32_bf16(af[kb], bo, acc[3],
                                                       0, 0, 0);
    }
    // ---- in-lane activation: lane holds (batch=(lane>>4)*4+e, col=gcol) ----
#pragma unroll
    for (int e = 0; e < 4; ++e) {
      float a0 = acc[0][e] + in_[0][e];
      float a1 = acc[1][e] + in_[1][e];
      float a2 = acc[2][e] + in_[2][e];
      float a3 = acc[3][e] + in_[3][e];
      float ig = fsig(a0);
      float fg = fsig(a1);
      float gg = ftanh(a2);
      float og = fsig(a3);
      float cn_ = fg * cs[e] + ig * gg;
      cs[e] = cn_;
      float hn = og * ftanh(cn_);
      unsigned short hb = f2bf(hn);
      if (lane < 32) {
        const int b = (lane >> 4) * 4 + e;  // 0..7
        hTn[b * 264 + gcol] = hb;
        const int bglob = bg * 8 + b;
        if (t < a.n0) {
          if (a.traj0)
            a.traj0[(size_t)t * (NB * NH) + (size_t)bglob * NH + gcol] = hb;
        } else if (a.traj1) {
          size_t idx = a.t1bmaj
              ? ((size_t)bglob * NDEC + (t - a.n0)) * NH + gcol
              : (size_t)(t - a.n0) * (NB * NH) + (size_t)bglob * NH + gcol;
          a.traj1[idx] = hb;
        }
      }
    }
    __syncthreads();
    cur ^= 1;
  }

  // ---- state save ----
  for (int i = tid; i < 8 * 256; i += 1024) {
    int b = i >> 8, col = i & 255;
    a.hSt[(size_t)(bg * 8 + b) * NH + col] = hTz[cur][b * 264 + col];
  }
  if (lane < 32) {
#pragma unroll
    for (int e = 0; e < 4; ++e)
      a.cSt[(size_t)(bg * 8 + (lane >> 4) * 4 + e) * NH + cbase + cn] = cs[e];
  }
}

__global__ __launch_bounds__(1024, 1) void p_lstm16(ChainArgs a) {
  __shared__ __align__(16) ushort_t WL[16 * 4096];
  __shared__ __align__(16) ushort_t hTz[2][16 * 264];
  run_chain(a, blockIdx.x, WL, hTz);
}

__global__ __launch_bounds__(1024, 1) void p_dual(ChainArgs a, ChainArgs b) {
  __shared__ __align__(16) ushort_t WL[16 * 4096];
  __shared__ __align__(16) ushort_t hTz[2][16 * 264];
  if (blockIdx.x < 16)
    run_chain(a, blockIdx.x, WL, hTz);
  else
    run_chain(b, blockIdx.x - 16, WL, hTz);
}

// ---------------- host ----------------

extern "C" void kernel_launch(void* const* d_in, const int* in_sizes, int n_in,
                              void* d_out, int out_size, void* d_ws,
                              size_t ws_size, hipStream_t stream) {
  const float* x = (const float*)d_in[0];
  const float* Wih1 = (const float*)d_in[1];
  const float* Whh1 = (const float*)d_in[2];
  const float* bih1 = (const float*)d_in[3];
  const float* bhh1 = (const float*)d_in[4];
  const float* Wih2 = (const float*)d_in[5];
  const float* Whh2 = (const float*)d_in[6];
  const float* bih2 = (const float*)d_in[7];
  const float* bhh2 = (const float*)d_in[8];
  const float* Wout = (const float*)d_in[9];
  const float* bout = (const float*)d_in[10];
  char* ws = (char*)d_ws;

  // ws layout (bytes). x_bf region reused for G2/G3 after G1 consumes it.
  ushort_t* x_bf   = (ushort_t*)(ws + 0);           //  83,886,080 (T,B,I) bf16
  float*    G2buf  = (float*)(ws + 0);              //  41,943,040 (after G1)
  float*    G3buf  = (float*)(ws + 41943040);       //  20,971,520 (after G1)
  float*    Gbuf   = (float*)(ws + 83886080);       //  41,943,040 (G1)
  ushort_t* Wih1b  = (ushort_t*)(ws + 125829120);   //   8,388,608
  ushort_t* Wih2b  = (ushort_t*)(ws + 134217728);   //     524,288
  ushort_t* Woutb  = (ushort_t*)(ws + 134742016);   //   3,080,192 (6016x256)
  ushort_t* Whh1b  = (ushort_t*)(ws + 137822208);   //     524,288
  ushort_t* Whh2b  = (ushort_t*)(ws + 138346496);   //     524,288
  ushort_t* ys1    = (ushort_t*)(ws + 138870784);   //   5,242,880 (80,128,256)
  ushort_t* H1dec  = (ushort_t*)(ws + 144113664);   //   2,686,976 (41,128,256)
  ushort_t* feats  = (ushort_t*)(ws + 146800640);   //   2,621,440 (128,40,256)
  ushort_t* Wsumb  = (ushort_t*)(ws + 149422080);   //     524,288 bf16(Wih2+Whh2)
  ushort_t* h1St   = (ushort_t*)(ws + 149946368);   //      65,536
  float*    c1St   = (float*)(ws + 150011904);      //     131,072
  ushort_t* h2St   = (ushort_t*)(ws + 150142976);   //      65,536
  float*    c2St   = (float*)(ws + 150208512);      //     131,072

  // casts + weight prep
  k_cast_x<<<dim3(NT, NB), 256, 0, stream>>>(x, x_bf);
  k_cast_pad<<<4096, 256, 0, stream>>>(Wih1, Wih1b, G4 * NI, G4 * NI);
  k_cast_pad<<<256, 256, 0, stream>>>(Wih2, Wih2b, G4 * NH, G4 * NH);
  k_cast_pad<<<1504, 256, 0, stream>>>(Wout, Woutb, NV * NH, NVP * NH);
  k_cast_pad<<<256, 256, 0, stream>>>(Whh1, Whh1b, G4 * NH, G4 * NH);
  k_cast_pad<<<256, 256, 0, stream>>>(Whh2, Whh2b, G4 * NH, G4 * NH);
  k_addw_bf<<<256, 256, 0, stream>>>(Wih2, Whh2, Wsumb);

  // G1 = x_bf @ Wih1^T + b1 : (10240, 1024), K=4096 (last use of x_bf/Wih1b)
  k_gemm<<<640, 256, 0, stream>>>(x_bf, Wih1b, Gbuf, bih1, bhh1, G4, NI, G4, 80);

  // chain-arg templates
  ChainArgs c1{Gbuf, nullptr, NT, 0, 0, Whh1b,
               bih1, bhh1, ys1, H1dec, 0, h1St, c1St};
  ChainArgs c2{G2buf, G3buf, NT, 0, 0, Whh2b,
               bih2, bhh2, nullptr, feats, 1, h2St, c2St};

  // 1) lstm1 encode steps 0..39
  ChainArgs e1a = c1; e1a.tStart = 0; e1a.tEnd = 40;
  p_lstm16<<<16, 1024, 0, stream>>>(e1a);

  // G2a = ys1[0:40] @ Wih2^T + b2
  k_gemm<<<320, 256, 0, stream>>>(ys1, Wih2b, G2buf, bih2, bhh2, G4, NH, G4, 40);

  // 2) lstm1 encode 40..79  ||  lstm2 encode 0..39
  ChainArgs e1b = c1; e1b.tStart = 40; e1b.tEnd = 80;
  ChainArgs e2a = c2; e2a.tStart = 0; e2a.tEnd = 40;
  p_dual<<<32, 1024, 0, stream>>>(e1b, e2a);

  // G2b = ys1[40:80] @ Wih2^T + b2
  k_gemm<<<320, 256, 0, stream>>>(ys1 + (size_t)40 * NB * NH, Wih2b,
                                  G2buf + (size_t)40 * NB * G4, bih2, bhh2,
                                  G4, NH, G4, 40);

  // 3) lstm1 pad 80..120 (41 steps) || lstm2 enc 40..79
  ChainArgs p1 = c1; p1.tStart = 80; p1.tEnd = 121;
  ChainArgs e2b = c2; e2b.tStart = 40; e2b.tEnd = 80;
  p_dual<<<32, 1024, 0, stream>>>(p1, e2b);

  // decode k=0 fold: H1dec[1] -= h2 (encoder-final) -> uniform Wsum decode
  k_subh<<<32, 256, 0, stream>>>(H1dec, h2St);

  // G3 = H1dec'[1..40] @ Wih2^T + b2
  k_gemm<<<320, 256, 0, stream>>>(H1dec + (size_t)NB * NH, Wih2b, G3buf, bih2,
                                  bhh2, G4, NH, G4, 40);

  // 4) lstm2 decode 80..119 (W = Wsumb throughout)
  ChainArgs d2 = c2; d2.W0 = Wsumb; d2.tStart = 80; d2.tEnd = 120;
  p_lstm16<<<16, 1024, 0, stream>>>(d2);

  // logits = feats @ Wout^T + b_out : (5120, 6000)
  k_gemm<<<40 * 47, 256, 0, stream>>>(feats, Woutb, (float*)d_out, bout, nullptr,
                                      NV, NH, NV, 40);
}

// Round 22
// 1183.473 us; speedup vs baseline: 1.4739x; 1.4739x over previous
//
#include <hip/hip_runtime.h>

#define NB 128
#define NT 80
#define NI 4096
#define NH 256
#define G4 1024
#define NV 6000
#define NVP 6016
#define NDEC 40

typedef unsigned short ushort_t;
typedef __attribute__((ext_vector_type(8))) short bf16x8;
typedef __attribute__((ext_vector_type(4))) float f32x4;

__device__ __forceinline__ unsigned short f2bf(float f) {
  unsigned int x = __float_as_uint(f);
  x += 0x7FFFu + ((x >> 16) & 1u);
  return (unsigned short)(x >> 16);
}
__device__ __forceinline__ float bf2f(ushort_t u) {
  return __uint_as_float(((unsigned)u) << 16);
}
__device__ __forceinline__ ushort4 pack4(float4 v) {
  return make_ushort4(f2bf(v.x), f2bf(v.y), f2bf(v.z), f2bf(v.w));
}
// fast activations: __expf + hw rcp (validated R13-R20: absmax unchanged)
__device__ __forceinline__ float ftanh(float x) {
  float xc = fminf(fmaxf(x, -12.f), 12.f);
  float e = __expf(2.f * xc);
  return (e - 1.f) * __builtin_amdgcn_rcpf(e + 1.f);
}
__device__ __forceinline__ float fsig(float x) {
  return __builtin_amdgcn_rcpf(1.f + __expf(-x));
}

// ---------------- cast / small kernels ----------------

__global__ __launch_bounds__(256) void k_cast_x(const float* __restrict__ x,
                                                ushort_t* __restrict__ xb) {
  const int t = blockIdx.x, b = blockIdx.y;
  const float* src = x + ((size_t)b * NT + t) * NI;
  ushort_t* dst = xb + ((size_t)t * NB + b) * NI;
#pragma unroll
  for (int s = 0; s < 4; ++s) {
    int j = s * 1024 + threadIdx.x * 4;
    float4 v = *(const float4*)(src + j);
    *(ushort4*)(dst + j) = pack4(v);
  }
}

__global__ __launch_bounds__(256) void k_cast_pad(const float* __restrict__ s,
                                                  ushort_t* __restrict__ d,
                                                  int nsrc, int ndst) {
  int i = (blockIdx.x * 256 + threadIdx.x) * 4;
  if (i >= ndst) return;
  ushort4 o;
  if (i < nsrc) {
    float4 v = *(const float4*)(s + i);
    o = pack4(v);
  } else {
    o = make_ushort4(0, 0, 0, 0);
  }
  *(ushort4*)(d + i) = o;
}

// o = bf16(a + b)
__global__ __launch_bounds__(256) void k_addw_bf(const float* __restrict__ a,
                                                 const float* __restrict__ b,
                                                 ushort_t* __restrict__ o) {
  int i = (blockIdx.x * 256 + threadIdx.x) * 4;
  float4 va = *(const float4*)(a + i);
  float4 vb = *(const float4*)(b + i);
  va.x += vb.x; va.y += vb.y; va.z += vb.z; va.w += vb.w;
  *(ushort4*)(o + i) = pack4(va);
}

// H1dec[1] -= h2St (bf16, in place; 128x256) — folds decode k=0 into Wsum form
__global__ __launch_bounds__(256) void k_subh(ushort_t* __restrict__ H1,
                                              const ushort_t* __restrict__ h2) {
  int i = (blockIdx.x * 256 + threadIdx.x) * 4;
  ushort_t* p = H1 + (size_t)NB * NH + i;
  const ushort_t* q = h2 + i;
#pragma unroll
  for (int k = 0; k < 4; ++k) p[k] = f2bf(bf2f(p[k]) - bf2f(q[k]));
}

// ---------------- bf16 MFMA GEMM: C = A @ B^T + bias_a + bias_b ----------------

#define GLDS(gp, lp)                                                     \
  __builtin_amdgcn_global_load_lds(                                      \
      (const __attribute__((address_space(1))) unsigned int*)(gp),       \
      (__attribute__((address_space(3))) unsigned int*)(lp), 16, 0, 0)

__global__ __launch_bounds__(256) void k_gemm(
    const ushort_t* __restrict__ A, const ushort_t* __restrict__ Bm,
    float* __restrict__ C, const float* __restrict__ ba,
    const float* __restrict__ bb, int Nreal, int K, int ldc, int mtiles) {
  __shared__ __align__(16) ushort_t Als[128 * 32];
  __shared__ __align__(16) ushort_t Bls[128 * 32];
  const int bid = blockIdx.x;
  const int mt = bid % mtiles, nt = bid / mtiles;
  const size_t m0 = (size_t)mt * 128, n0 = (size_t)nt * 128;
  const int tid = threadIdx.x, wave = tid >> 6, lane = tid & 63;
  const int wm = (wave & 1) * 64, wn = (wave >> 1) * 64;
  const int srow = wave * 16 + (lane >> 2), skcol = (lane & 3) * 8;
  const int fr = lane & 15, kb = (lane >> 4) * 8;

  f32x4 acc[4][4];
#pragma unroll
  for (int i = 0; i < 4; ++i)
#pragma unroll
    for (int j = 0; j < 4; ++j) acc[i][j] = (f32x4){0.f, 0.f, 0.f, 0.f};

  for (int kk = 0; kk < K; kk += 32) {
    __syncthreads();
#pragma unroll
    for (int p = 0; p < 2; ++p) {
      GLDS(A + (m0 + p * 64 + srow) * K + kk + skcol,
           &Als[(p * 64 + wave * 16) * 32]);
      GLDS(Bm + (n0 + p * 64 + srow) * K + kk + skcol,
           &Bls[(p * 64 + wave * 16) * 32]);
    }
    __syncthreads();
    bf16x8 af[4], bfr[4];
#pragma unroll
    for (int i = 0; i < 4; ++i)
      af[i] = *(const bf16x8*)&Als[(wm + i * 16 + fr) * 32 + kb];
#pragma unroll
    for (int j = 0; j < 4; ++j)
      bfr[j] = *(const bf16x8*)&Bls[(wn + j * 16 + fr) * 32 + kb];
#pragma unroll
    for (int i = 0; i < 4; ++i)
#pragma unroll
      for (int j = 0; j < 4; ++j)
        acc[i][j] = __builtin_amdgcn_mfma_f32_16x16x32_bf16(af[i], bfr[j],
                                                            acc[i][j], 0, 0, 0);
  }
  const int cr4 = (lane >> 4) * 4, ccn = lane & 15;
#pragma unroll
  for (int j = 0; j < 4; ++j) {
    int n = (int)n0 + wn + j * 16 + ccn;
    if (n < Nreal) {
      float bv = (ba ? ba[n] : 0.f) + (bb ? bb[n] : 0.f);
#pragma unroll
      for (int i = 0; i < 4; ++i) {
#pragma unroll
        for (int r = 0; r < 4; ++r) {
          size_t m = m0 + wm + i * 16 + cr4 + r;
          C[m * (size_t)ldc + n] = acc[i][j][r] + bv;
        }
      }
    }
  }
}

// ---------------- persistent LSTM chain (chunked; R20 champion config) --------
// 8 waves x 512 thr, (512,1): VGPR 128 — the allocator's best budget (R21/R13:
// 16 waves -> 64 regs, 2x worse; R14: in-loop W loads 2x worse; R12: manual
// vmcnt 2x worse). Chunked 161-sequential-step schedule; builtin MFMA only;
// no mid-chunk W switch (k_subh fold).

struct ChainArgs {
  const float* gIn0; const float* gIn1; int n0; int tStart; int tEnd;
  const ushort_t* W0;
  const float* biasA; const float* biasB;
  ushort_t* traj0; ushort_t* traj1; int t1bmaj;
  ushort_t* hSt; float* cSt;
};

#define LOAD_WREGS(Wb)                                                        \
  _Pragma("unroll") for (int g = 0; g < 3; ++g)                               \
  _Pragma("unroll") for (int h = 0; h < 2; ++h)                               \
  _Pragma("unroll") for (int kb = 0; kb < 8; ++kb)                            \
      wr[g * 2 + h][kb] = *(const bf16x8*)((Wb) +                             \
          (size_t)(g * 256 + cbase + h * 16 + cn) * NH + kb * 32 + kgrp * 8);

#define PIN_W()                                                               \
  _Pragma("unroll") for (int g = 0; g < 6; ++g)                               \
  _Pragma("unroll") for (int kb = 0; kb < 8; ++kb)                            \
      asm volatile("" : "+a"(wr[g][kb]));

#define LOAD_WLDS(Wb)                                                         \
  _Pragma("unroll") for (int h = 0; h < 2; ++h)                               \
  _Pragma("unroll") for (int kb = 0; kb < 8; ++kb)                            \
      *(bf16x8*)&WL[wv * 8192 + h * 4096 + kb * 512 + cn * 32 + kgrp * 8] =   \
          *(const bf16x8*)((Wb) +                                             \
          (size_t)(768 + cbase + h * 16 + cn) * NH + kb * 32 + kgrp * 8);

__device__ __forceinline__ void run_chain(const ChainArgs a, int bg,
                                          ushort_t* WL,
                                          ushort_t (*hTz)[16 * 264]) {
  const int tid = threadIdx.x;
  const int wv = tid >> 6, lane = tid & 63;
  const int cn = lane & 15;               // B col / A row / C col
  const int kgrp = lane >> 4;             // 0..3 (k slice)
  const int cbase = wv * 32;
  const int rsel = kgrp & 1;              // batch-row group for G loads

  bf16x8 wr[6][8];
  LOAD_WREGS(a.W0);
  PIN_W();
  LOAD_WLDS(a.W0);

  // ---- state init / restore (barrier between: R16 race fix) ----
  for (int i = tid; i < 2 * 16 * 264; i += 512) ((ushort_t*)hTz)[i] = 0;
  __syncthreads();
  float cs[8];
  if (a.tStart == 0) {
#pragma unroll
    for (int i = 0; i < 8; ++i) cs[i] = 0.f;
  } else {
    for (int i = tid; i < 8 * 256; i += 512) {
      int b = i >> 8, col = i & 255;
      hTz[0][b * 264 + col] = a.hSt[(size_t)(bg * 8 + b) * NH + col];
    }
#pragma unroll
    for (int h = 0; h < 2; ++h)
#pragma unroll
      for (int e = 0; e < 4; ++e)
        cs[h * 4 + e] =
            a.cSt[(size_t)(bg * 8 + rsel * 4 + e) * NH + cbase + h * 16 + cn];
  }
  __syncthreads();

  int cur = 0;
  for (int t = a.tStart; t < a.tEnd; ++t) {
    const ushort_t* hTc = &hTz[cur][0];
    ushort_t* hTn = &hTz[cur ^ 1][0];
    const float* gseg = (t < a.n0) ? a.gIn0 : a.gIn1;
    const int tt = (t < a.n0) ? t : t - a.n0;
#pragma unroll
    for (int h = 0; h < 2; ++h) {
      const int gcol = cbase + h * 16 + cn;
      float in_[4][4];
      if (gseg) {
        const float* base = gseg + (size_t)tt * (NB * G4);
#pragma unroll
        for (int g = 0; g < 4; ++g)
#pragma unroll
          for (int e = 0; e < 4; ++e)
            in_[g][e] = base[(size_t)(bg * 8 + rsel * 4 + e) * G4 + g * 256 + gcol];
      } else {
#pragma unroll
        for (int g = 0; g < 4; ++g) {
          float b = a.biasA[g * 256 + gcol] + a.biasB[g * 256 + gcol];
#pragma unroll
          for (int e = 0; e < 4; ++e) in_[g][e] = b;
        }
      }
      f32x4 acc[4];
#pragma unroll
      for (int g = 0; g < 4; ++g) acc[g] = (f32x4){0.f, 0.f, 0.f, 0.f};
#pragma unroll
      for (int kb = 0; kb < 8; ++kb) {
        bf16x8 af = *(const bf16x8*)&hTc[cn * 264 + kb * 32 + kgrp * 8];
        bf16x8 bo = *(const bf16x8*)&WL[wv * 8192 + h * 4096 + kb * 512 +
                                        cn * 32 + kgrp * 8];
        acc[0] = __builtin_amdgcn_mfma_f32_16x16x32_bf16(af, wr[0 + h][kb],
                                                         acc[0], 0, 0, 0);
        acc[1] = __builtin_amdgcn_mfma_f32_16x16x32_bf16(af, wr[2 + h][kb],
                                                         acc[1], 0, 0, 0);
        acc[2] = __builtin_amdgcn_mfma_f32_16x16x32_bf16(af, wr[4 + h][kb],
                                                         acc[2], 0, 0, 0);
        acc[3] = __builtin_amdgcn_mfma_f32_16x16x32_bf16(af, bo, acc[3], 0, 0, 0);
      }
      // in-lane activation: lane holds (batch=(lane>>4)*4+e, col=gcol)
#pragma unroll
      for (int e = 0; e < 4; ++e) {
        float a0 = acc[0][e] + in_[0][e];
        float a1 = acc[1][e] + in_[1][e];
        float a2 = acc[2][e] + in_[2][e];
        float a3 = acc[3][e] + in_[3][e];
        float ig = fsig(a0);
        float fg = fsig(a1);
        float gg = ftanh(a2);
        float og = fsig(a3);
        float cn_ = fg * cs[h * 4 + e] + ig * gg;
        cs[h * 4 + e] = cn_;
        float hn = og * ftanh(cn_);
        unsigned short hb = f2bf(hn);
        if (lane < 32) {
          const int b = (lane >> 4) * 4 + e;  // 0..7
          hTn[b * 264 + gcol] = hb;
          const int bglob = bg * 8 + b;
          if (t < a.n0) {
            if (a.traj0)
              a.traj0[(size_t)t * (NB * NH) + (size_t)bglob * NH + gcol] = hb;
          } else if (a.traj1) {
            size_t idx = a.t1bmaj
                ? ((size_t)bglob * NDEC + (t - a.n0)) * NH + gcol
                : (size_t)(t - a.n0) * (NB * NH) + (size_t)bglob * NH + gcol;
            a.traj1[idx] = hb;
          }
        }
      }
    }
    __syncthreads();
    cur ^= 1;
  }

  // ---- state save ----
  for (int i = tid; i < 8 * 256; i += 512) {
    int b = i >> 8, col = i & 255;
    a.hSt[(size_t)(bg * 8 + b) * NH + col] = hTz[cur][b * 264 + col];
  }
  if (lane < 32) {
#pragma unroll
    for (int h = 0; h < 2; ++h)
#pragma unroll
      for (int e = 0; e < 4; ++e)
        a.cSt[(size_t)(bg * 8 + (lane >> 4) * 4 + e) * NH + cbase + h * 16 + cn] =
            cs[h * 4 + e];
  }
}

__global__ __launch_bounds__(512, 1) void p_lstm16(ChainArgs a) {
  __shared__ __align__(16) ushort_t WL[8 * 8192];
  __shared__ __align__(16) ushort_t hTz[2][16 * 264];
  run_chain(a, blockIdx.x, WL, hTz);
}

__global__ __launch_bounds__(512, 1) void p_dual(ChainArgs a, ChainArgs b) {
  __shared__ __align__(16) ushort_t WL[8 * 8192];
  __shared__ __align__(16) ushort_t hTz[2][16 * 264];
  if (blockIdx.x < 16)
    run_chain(a, blockIdx.x, WL, hTz);
  else
    run_chain(b, blockIdx.x - 16, WL, hTz);
}

// ---------------- host ----------------

extern "C" void kernel_launch(void* const* d_in, const int* in_sizes, int n_in,
                              void* d_out, int out_size, void* d_ws,
                              size_t ws_size, hipStream_t stream) {
  const float* x = (const float*)d_in[0];
  const float* Wih1 = (const float*)d_in[1];
  const float* Whh1 = (const float*)d_in[2];
  const float* bih1 = (const float*)d_in[3];
  const float* bhh1 = (const float*)d_in[4];
  const float* Wih2 = (const float*)d_in[5];
  const float* Whh2 = (const float*)d_in[6];
  const float* bih2 = (const float*)d_in[7];
  const float* bhh2 = (const float*)d_in[8];
  const float* Wout = (const float*)d_in[9];
  const float* bout = (const float*)d_in[10];
  char* ws = (char*)d_ws;

  // ws layout (bytes). x_bf region reused for G2/G3 after G1 consumes it.
  ushort_t* x_bf   = (ushort_t*)(ws + 0);           //  83,886,080 (T,B,I) bf16
  float*    G2buf  = (float*)(ws + 0);              //  41,943,040 (after G1)
  float*    G3buf  = (float*)(ws + 41943040);       //  20,971,520 (after G1)
  float*    Gbuf   = (float*)(ws + 83886080);       //  41,943,040 (G1)
  ushort_t* Wih1b  = (ushort_t*)(ws + 125829120);   //   8,388,608
  ushort_t* Wih2b  = (ushort_t*)(ws + 134217728);   //     524,288
  ushort_t* Woutb  = (ushort_t*)(ws + 134742016);   //   3,080,192 (6016x256)
  ushort_t* Whh1b  = (ushort_t*)(ws + 137822208);   //     524,288
  ushort_t* Whh2b  = (ushort_t*)(ws + 138346496);   //     524,288
  ushort_t* ys1    = (ushort_t*)(ws + 138870784);   //   5,242,880 (80,128,256)
  ushort_t* H1dec  = (ushort_t*)(ws + 144113664);   //   2,686,976 (41,128,256)
  ushort_t* feats  = (ushort_t*)(ws + 146800640);   //   2,621,440 (128,40,256)
  ushort_t* Wsumb  = (ushort_t*)(ws + 149422080);   //     524,288 bf16(Wih2+Whh2)
  ushort_t* h1St   = (ushort_t*)(ws + 149946368);   //      65,536
  float*    c1St   = (float*)(ws + 150011904);      //     131,072
  ushort_t* h2St   = (ushort_t*)(ws + 150142976);   //      65,536
  float*    c2St   = (float*)(ws + 150208512);      //     131,072

  // casts + weight prep
  k_cast_x<<<dim3(NT, NB), 256, 0, stream>>>(x, x_bf);
  k_cast_pad<<<4096, 256, 0, stream>>>(Wih1, Wih1b, G4 * NI, G4 * NI);
  k_cast_pad<<<256, 256, 0, stream>>>(Wih2, Wih2b, G4 * NH, G4 * NH);
  k_cast_pad<<<1504, 256, 0, stream>>>(Wout, Woutb, NV * NH, NVP * NH);
  k_cast_pad<<<256, 256, 0, stream>>>(Whh1, Whh1b, G4 * NH, G4 * NH);
  k_cast_pad<<<256, 256, 0, stream>>>(Whh2, Whh2b, G4 * NH, G4 * NH);
  k_addw_bf<<<256, 256, 0, stream>>>(Wih2, Whh2, Wsumb);

  // G1 = x_bf @ Wih1^T + b1 : (10240, 1024), K=4096 (last use of x_bf/Wih1b)
  k_gemm<<<640, 256, 0, stream>>>(x_bf, Wih1b, Gbuf, bih1, bhh1, G4, NI, G4, 80);

  // chain-arg templates
  ChainArgs c1{Gbuf, nullptr, NT, 0, 0, Whh1b,
               bih1, bhh1, ys1, H1dec, 0, h1St, c1St};
  ChainArgs c2{G2buf, G3buf, NT, 0, 0, Whh2b,
               bih2, bhh2, nullptr, feats, 1, h2St, c2St};

  // 1) lstm1 encode steps 0..39
  ChainArgs e1a = c1; e1a.tStart = 0; e1a.tEnd = 40;
  p_lstm16<<<16, 512, 0, stream>>>(e1a);

  // G2a = ys1[0:40] @ Wih2^T + b2
  k_gemm<<<320, 256, 0, stream>>>(ys1, Wih2b, G2buf, bih2, bhh2, G4, NH, G4, 40);

  // 2) lstm1 encode 40..79  ||  lstm2 encode 0..39
  ChainArgs e1b = c1; e1b.tStart = 40; e1b.tEnd = 80;
  ChainArgs e2a = c2; e2a.tStart = 0; e2a.tEnd = 40;
  p_dual<<<32, 512, 0, stream>>>(e1b, e2a);

  // G2b = ys1[40:80] @ Wih2^T + b2
  k_gemm<<<320, 256, 0, stream>>>(ys1 + (size_t)40 * NB * NH, Wih2b,
                                  G2buf + (size_t)40 * NB * G4, bih2, bhh2,
                                  G4, NH, G4, 40);

  // 3) lstm1 pad 80..120 (41 steps) || lstm2 enc 40..79
  ChainArgs p1 = c1; p1.tStart = 80; p1.tEnd = 121;
  ChainArgs e2b = c2; e2b.tStart = 40; e2b.tEnd = 80;
  p_dual<<<32, 512, 0, stream>>>(p1, e2b);

  // decode k=0 fold: H1dec[1] -= h2 (encoder-final) -> uniform Wsum decode
  k_subh<<<32, 256, 0, stream>>>(H1dec, h2St);

  // G3 = H1dec'[1..40] @ Wih2^T + b2
  k_gemm<<<320, 256, 0, stream>>>(H1dec + (size_t)NB * NH, Wih2b, G3buf, bih2,
                                  bhh2, G4, NH, G4, 40);

  // 4) lstm2 decode 80..119 (W = Wsumb throughout)
  ChainArgs d2 = c2; d2.W0 = Wsumb; d2.tStart = 80; d2.tEnd = 120;
  p_lstm16<<<16, 512, 0, stream>>>(d2);

  // logits = feats @ Wout^T + b_out : (5120, 6000)
  k_gemm<<<40 * 47, 256, 0, stream>>>(feats, Woutb, (float*)d_out, bout, nullptr,
                                      NV, NH, NV, 40);
}